// Round 6
// baseline (33.923 us; speedup 1.0000x reference)
//
#include <hip/hip_runtime.h>
#include <cstdint>

// Soft_Att: B=128, T=2048, D=256
#define BB 128
#define TT 2048
#define DD 256
#define NCHUNK 8                 // T-chunks per batch -> 1024 blocks
#define TC (TT / NCHUNK)         // 256 rows per block
#define NPART (BB * NCHUNK)      // 1024 partials

// ws layout (floats): ms[NPART] | ls[NPART] | zs[NPART * DD]

__device__ __forceinline__ int rowOf(const uint4& lw, int s) {
    s &= 15;
    unsigned word = (s & 8) ? ((s & 4) ? lw.w : lw.z)
                            : ((s & 4) ? lw.y : lw.x);
    return (int)((word >> ((s & 3) * 8)) & 255u);
}

__global__ __launch_bounds__(256) void soft_att_partial(
    const float* __restrict__ h,      // [B, D]
    const float* __restrict__ htraj,  // [B, T, D]
    const int*   __restrict__ mask,   // [B, T]  (nonzero = masked)
    const float* __restrict__ w,      // [D]
    const float* __restrict__ bias,   // [1]
    float* __restrict__ msv,          // [NPART]
    float* __restrict__ lsv,          // [NPART]
    float* __restrict__ zsv)          // [NPART, D]
{
    const int blk  = blockIdx.x;
    const int b    = blk / NCHUNK;
    const int c    = blk % NCHUNK;
    const int tid  = threadIdx.x;
    const int lane = tid & 63;
    const int wv   = tid >> 6;       // wave 0..3
    const int i    = lane & 15;      // lane within 16-lane group
    const int grp  = tid >> 4;       // group within block (0..15)

    // lane's slice of (h[b] * w): dims { j*64 + i*4 .. +3 }, j=0..3
    const float* hb = h + (size_t)b * DD + i * 4;
    const float* wb = w + i * 4;
    float4 hw0, hw1, hw2, hw3;
    {
        float4 h0 = *(const float4*)(hb);       float4 w0 = *(const float4*)(wb);
        float4 h1 = *(const float4*)(hb + 64);  float4 w1 = *(const float4*)(wb + 64);
        float4 h2 = *(const float4*)(hb + 128); float4 w2 = *(const float4*)(wb + 128);
        float4 h3 = *(const float4*)(hb + 192); float4 w3 = *(const float4*)(wb + 192);
        hw0 = make_float4(h0.x*w0.x, h0.y*w0.y, h0.z*w0.z, h0.w*w0.w);
        hw1 = make_float4(h1.x*w1.x, h1.y*w1.y, h1.z*w1.z, h1.w*w1.w);
        hw2 = make_float4(h2.x*w2.x, h2.y*w2.y, h2.z*w2.z, h2.w*w2.w);
        hw3 = make_float4(h3.x*w3.x, h3.y*w3.y, h3.z*w3.z, h3.w*w3.w);
    }
    const float bscal = bias[0];

    // ---- block-wide live-row list: deal live rows round-robin to 16 groups ----
    __shared__ unsigned long long wballot[4];
    __shared__ unsigned char lists[16][16];   // [group][slot] -> row in chunk
    __shared__ float sm[16];
    __shared__ float sl[16];
    __shared__ float sz[16][DD];              // 16 KB

    const int row = tid;                      // row within this 256-row chunk
    const int mk  = mask[(size_t)b * TT + c * TC + row];
    unsigned long long bt = __ballot(mk == 0);
    if (lane == 0) wballot[wv] = bt;
    __syncthreads();
    int prev = 0, tot = 0;
    #pragma unroll
    for (int k = 0; k < 4; ++k) {
        int pc = __popcll(wballot[k]);
        prev += (k < wv) ? pc : 0;
        tot  += pc;
    }
    const int rank = prev + __popcll(bt & ((1ull << lane) - 1ull));
    if (mk == 0) lists[rank & 15][rank >> 4] = (unsigned char)row;
    __syncthreads();

    const int cntmax = (tot + 15) >> 4;                    // uniform per block
    const int mycnt  = (tot > grp) ? ((tot - grp + 15) >> 4) : 0;
    const uint4 lw = *(const uint4*)&lists[grp][0];        // broadcast b128

    const float* chunkbase = htraj + ((size_t)b * TT + c * TC) * DD + i * 4;

    float m = -3.0e38f, l = 0.0f;
    float4 a0 = make_float4(0,0,0,0), a1 = a0, a2 = a0, a3 = a0;

#define LOADV(V0_, V1_, V2_, V3_, r_, ok_) { \
    if (ok_) { const float* p_ = chunkbase + (size_t)(r_) * DD; \
        V0_ = *(const float4*)(p_); \
        V1_ = *(const float4*)(p_ + 64); \
        V2_ = *(const float4*)(p_ + 128); \
        V3_ = *(const float4*)(p_ + 192); } }

#define PROC(V0_, V1_, V2_, V3_, ok_) { \
    float s0_ = V0_.x*hw0.x; s0_ = fmaf(V0_.y,hw0.y,s0_); s0_ = fmaf(V0_.z,hw0.z,s0_); s0_ = fmaf(V0_.w,hw0.w,s0_); \
    float s1_ = V1_.x*hw1.x; s1_ = fmaf(V1_.y,hw1.y,s1_); s1_ = fmaf(V1_.z,hw1.z,s1_); s1_ = fmaf(V1_.w,hw1.w,s1_); \
    float s2_ = V2_.x*hw2.x; s2_ = fmaf(V2_.y,hw2.y,s2_); s2_ = fmaf(V2_.z,hw2.z,s2_); s2_ = fmaf(V2_.w,hw2.w,s2_); \
    float s3_ = V3_.x*hw3.x; s3_ = fmaf(V3_.y,hw3.y,s3_); s3_ = fmaf(V3_.z,hw3.z,s3_); s3_ = fmaf(V3_.w,hw3.w,s3_); \
    float s_ = (s0_ + s1_) + (s2_ + s3_); \
    s_ += __shfl_xor(s_, 1, 64); \
    s_ += __shfl_xor(s_, 2, 64); \
    s_ += __shfl_xor(s_, 4, 64); \
    s_ += __shfl_xor(s_, 8, 64); \
    s_ = (ok_) ? s_ + bscal : -INFINITY; \
    float mn_ = fmaxf(m, s_); \
    float sc_ = __expf(m - mn_); \
    float p_  = __expf(s_ - mn_); \
    a0.x = fmaf(a0.x, sc_, p_*V0_.x); a0.y = fmaf(a0.y, sc_, p_*V0_.y); \
    a0.z = fmaf(a0.z, sc_, p_*V0_.z); a0.w = fmaf(a0.w, sc_, p_*V0_.w); \
    a1.x = fmaf(a1.x, sc_, p_*V1_.x); a1.y = fmaf(a1.y, sc_, p_*V1_.y); \
    a1.z = fmaf(a1.z, sc_, p_*V1_.z); a1.w = fmaf(a1.w, sc_, p_*V1_.w); \
    a2.x = fmaf(a2.x, sc_, p_*V2_.x); a2.y = fmaf(a2.y, sc_, p_*V2_.y); \
    a2.z = fmaf(a2.z, sc_, p_*V2_.z); a2.w = fmaf(a2.w, sc_, p_*V2_.w); \
    a3.x = fmaf(a3.x, sc_, p_*V3_.x); a3.y = fmaf(a3.y, sc_, p_*V3_.y); \
    a3.z = fmaf(a3.z, sc_, p_*V3_.z); a3.w = fmaf(a3.w, sc_, p_*V3_.w); \
    l = fmaf(l, sc_, p_); m = mn_; }

    // 4-deep rotating software pipeline: 3 row-buffers in flight ahead of PROC
    float4 A0 = make_float4(0,0,0,0), A1 = A0, A2 = A0, A3 = A0;
    float4 B0 = A0, B1 = A0, B2 = A0, B3 = A0;
    float4 C0 = A0, C1 = A0, C2 = A0, C3 = A0;
    float4 D0 = A0, D1 = A0, D2 = A0, D3 = A0;

    bool okA = (0 < mycnt), okB = (1 < mycnt), okC = (2 < mycnt), okD = false;
    if (okA) { int r = rowOf(lw, 0); LOADV(A0, A1, A2, A3, r, okA); }
    if (okB) { int r = rowOf(lw, 1); LOADV(B0, B1, B2, B3, r, okB); }
    if (okC) { int r = rowOf(lw, 2); LOADV(C0, C1, C2, C3, r, okC); }

    int it = 0;
    while (it < cntmax) {
        okD = (it + 3 < mycnt);
        if (okD) { int r = rowOf(lw, it + 3); LOADV(D0, D1, D2, D3, r, okD); }
        PROC(A0, A1, A2, A3, okA);
        if (++it >= cntmax) break;

        okA = (it + 3 < mycnt);
        if (okA) { int r = rowOf(lw, it + 3); LOADV(A0, A1, A2, A3, r, okA); }
        PROC(B0, B1, B2, B3, okB);
        if (++it >= cntmax) break;

        okB = (it + 3 < mycnt);
        if (okB) { int r = rowOf(lw, it + 3); LOADV(B0, B1, B2, B3, r, okB); }
        PROC(C0, C1, C2, C3, okC);
        if (++it >= cntmax) break;

        okC = (it + 3 < mycnt);
        if (okC) { int r = rowOf(lw, it + 3); LOADV(C0, C1, C2, C3, r, okC); }
        PROC(D0, D1, D2, D3, okD);
        ++it;
    }

    // --- merge the block's 16 group-partials via LDS ---
    *(float4*)&sz[grp][i * 4      ] = a0;
    *(float4*)&sz[grp][i * 4 + 64 ] = a1;
    *(float4*)&sz[grp][i * 4 + 128] = a2;
    *(float4*)&sz[grp][i * 4 + 192] = a3;
    if (i == 0) { sm[grp] = m; sl[grp] = l; }
    __syncthreads();

    // thread tid owns output dim d = tid
    float M = -3.0e38f;
    #pragma unroll
    for (int k = 0; k < 16; ++k) M = fmaxf(M, sm[k]);
    float L = 0.f, Z = 0.f;
    #pragma unroll
    for (int k = 0; k < 16; ++k) {
        float e = __expf(sm[k] - M);   // empty group: l=0 kills it
        L = fmaf(sl[k], e, L);
        Z = fmaf(sz[k][tid], e, Z);
    }
    if (tid == 0) { msv[blk] = M; lsv[blk] = L; }
    zsv[(size_t)blk * DD + tid] = Z;
#undef LOADV
#undef PROC
}

__global__ __launch_bounds__(128) void soft_att_combine(
    const float* __restrict__ msv,
    const float* __restrict__ lsv,
    const float* __restrict__ zsv,
    float* __restrict__ out)          // [B, D]
{
    const int blk = blockIdx.x;           // 256 blocks: (b, half)
    const int b   = blk >> 1;
    const int d   = ((blk & 1) << 7) + threadIdx.x;

    float M = -3.0e38f;
    #pragma unroll
    for (int p = 0; p < NCHUNK; ++p)
        M = fmaxf(M, msv[b * NCHUNK + p]);

    float L = 0.f, Z = 0.f;
    #pragma unroll
    for (int p = 0; p < NCHUNK; ++p) {
        float e = __expf(msv[b * NCHUNK + p] - M);
        L = fmaf(lsv[b * NCHUNK + p], e, L);
        Z = fmaf(zsv[(size_t)(b * NCHUNK + p) * DD + d], e, Z);
    }
    out[(size_t)b * DD + d] = Z / L;
}

extern "C" void kernel_launch(void* const* d_in, const int* in_sizes, int n_in,
                              void* d_out, int out_size, void* d_ws, size_t ws_size,
                              hipStream_t stream) {
    const float* h     = (const float*)d_in[0];
    const float* htraj = (const float*)d_in[1];
    const int*   mask  = (const int*)d_in[2];
    const float* w     = (const float*)d_in[3];
    const float* bias  = (const float*)d_in[4];
    float* out = (float*)d_out;

    float* ms = (float*)d_ws;
    float* ls = ms + NPART;
    float* zs = ls + NPART;

    soft_att_partial<<<dim3(BB * NCHUNK), dim3(256), 0, stream>>>(
        h, htraj, mask, w, bias, ms, ls, zs);
    soft_att_combine<<<dim3(BB * 2), dim3(128), 0, stream>>>(ms, ls, zs, out);
}

// Round 7
// 30.365 us; speedup vs baseline: 1.1172x; 1.1172x over previous
//
#include <hip/hip_runtime.h>
#include <cstdint>

// Soft_Att: B=128, T=2048, D=256
#define BB 128
#define TT 2048
#define DD 256
#define NCHUNK 16                // T-chunks per batch -> 2048 blocks
#define TC (TT / NCHUNK)         // 128 rows per block (2 waves x 64)
#define NPART (BB * NCHUNK)      // 2048 partials

// ws layout (floats): ms[NPART] | ls[NPART] | zs[NPART * DD]  (~2.1 MB)

__global__ __launch_bounds__(128) void soft_att_partial(
    const float* __restrict__ h,      // [B, D]
    const float* __restrict__ htraj,  // [B, T, D]
    const int*   __restrict__ mask,   // [B, T]  (nonzero = masked)
    const float* __restrict__ w,      // [D]
    const float* __restrict__ bias,   // [1]
    float* __restrict__ msv,          // [NPART]
    float* __restrict__ lsv,          // [NPART]
    float* __restrict__ zsv)          // [NPART, D]
{
    const int blk  = blockIdx.x;
    const int b    = blk / NCHUNK;
    const int c    = blk % NCHUNK;
    const int tid  = threadIdx.x;
    const int lane = tid & 63;
    const int wv   = tid >> 6;       // wave 0..1
    const int g    = lane >> 4;      // 16-lane group within wave (0..3)
    const int i    = lane & 15;      // lane within group
    const int grp  = tid >> 4;       // group within block (0..7)

    // lane's slice of (h[b] * w): dims { j*64 + i*4 .. +3 }, j=0..3
    const float* hb = h + (size_t)b * DD + i * 4;
    const float* wb = w + i * 4;
    float4 hw0, hw1, hw2, hw3;
    {
        float4 h0 = *(const float4*)(hb);       float4 w0 = *(const float4*)(wb);
        float4 h1 = *(const float4*)(hb + 64);  float4 w1 = *(const float4*)(wb + 64);
        float4 h2 = *(const float4*)(hb + 128); float4 w2 = *(const float4*)(wb + 128);
        float4 h3 = *(const float4*)(hb + 192); float4 w3 = *(const float4*)(wb + 192);
        hw0 = make_float4(h0.x*w0.x, h0.y*w0.y, h0.z*w0.z, h0.w*w0.w);
        hw1 = make_float4(h1.x*w1.x, h1.y*w1.y, h1.z*w1.z, h1.w*w1.w);
        hw2 = make_float4(h2.x*w2.x, h2.y*w2.y, h2.z*w2.z, h2.w*w2.w);
        hw3 = make_float4(h3.x*w3.x, h3.y*w3.y, h3.z*w3.z, h3.w*w3.w);
    }
    const float bscal = bias[0];

    const int t0 = c * TC + wv * 64;              // this wave's 64-row tile
    const int mk = mask[(size_t)b * TT + t0 + lane];
    unsigned long long bits = __ballot(mk == 0);  // live-row bitmap (uniform)

    const float* rowbase = htraj + ((size_t)b * TT + t0) * DD + i * 4;

    float m = -3.0e38f, l = 0.0f;
    float4 a0 = make_float4(0,0,0,0), a1 = a0, a2 = a0, a3 = a0;

    // deal live rows round-robin to the 4 groups; ~live/4 iterations
    const int n = (int)((__popcll(bits) + 3) >> 2);

#define POP(r_, ok_) { \
    unsigned long long b0_ = bits; \
    unsigned long long b1_ = b0_ & (b0_ - 1); \
    unsigned long long b2_ = b1_ & (b1_ - 1); \
    unsigned long long b3_ = b2_ & (b2_ - 1); \
    int r0_ = b0_ ? __builtin_ctzll(b0_) : 0; \
    int r1_ = b1_ ? __builtin_ctzll(b1_) : 0; \
    int r2_ = b2_ ? __builtin_ctzll(b2_) : 0; \
    int r3_ = b3_ ? __builtin_ctzll(b3_) : 0; \
    bits = b3_ & (b3_ - 1); \
    r_  = (g & 2) ? ((g & 1) ? r3_ : r2_) : ((g & 1) ? r1_ : r0_); \
    ok_ = (g & 2) ? ((g & 1) ? (b3_ != 0) : (b2_ != 0)) \
                  : ((g & 1) ? (b1_ != 0) : (b0_ != 0)); }

#define LOADV(V0_, V1_, V2_, V3_, r_, ok_) { \
    if (ok_) { const float* p_ = rowbase + (size_t)(r_) * DD; \
        V0_ = *(const float4*)(p_); \
        V1_ = *(const float4*)(p_ + 64); \
        V2_ = *(const float4*)(p_ + 128); \
        V3_ = *(const float4*)(p_ + 192); } }

#define PROC(V0_, V1_, V2_, V3_, ok_) { \
    float s0_ = V0_.x*hw0.x; s0_ = fmaf(V0_.y,hw0.y,s0_); s0_ = fmaf(V0_.z,hw0.z,s0_); s0_ = fmaf(V0_.w,hw0.w,s0_); \
    float s1_ = V1_.x*hw1.x; s1_ = fmaf(V1_.y,hw1.y,s1_); s1_ = fmaf(V1_.z,hw1.z,s1_); s1_ = fmaf(V1_.w,hw1.w,s1_); \
    float s2_ = V2_.x*hw2.x; s2_ = fmaf(V2_.y,hw2.y,s2_); s2_ = fmaf(V2_.z,hw2.z,s2_); s2_ = fmaf(V2_.w,hw2.w,s2_); \
    float s3_ = V3_.x*hw3.x; s3_ = fmaf(V3_.y,hw3.y,s3_); s3_ = fmaf(V3_.z,hw3.z,s3_); s3_ = fmaf(V3_.w,hw3.w,s3_); \
    float s_ = (s0_ + s1_) + (s2_ + s3_); \
    s_ += __shfl_xor(s_, 1, 64); \
    s_ += __shfl_xor(s_, 2, 64); \
    s_ += __shfl_xor(s_, 4, 64); \
    s_ += __shfl_xor(s_, 8, 64); \
    s_ = (ok_) ? s_ + bscal : -INFINITY; \
    float mn_ = fmaxf(m, s_); \
    float sc_ = __expf(m - mn_); \
    float p_  = __expf(s_ - mn_); \
    a0.x = fmaf(a0.x, sc_, p_*V0_.x); a0.y = fmaf(a0.y, sc_, p_*V0_.y); \
    a0.z = fmaf(a0.z, sc_, p_*V0_.z); a0.w = fmaf(a0.w, sc_, p_*V0_.w); \
    a1.x = fmaf(a1.x, sc_, p_*V1_.x); a1.y = fmaf(a1.y, sc_, p_*V1_.y); \
    a1.z = fmaf(a1.z, sc_, p_*V1_.z); a1.w = fmaf(a1.w, sc_, p_*V1_.w); \
    a2.x = fmaf(a2.x, sc_, p_*V2_.x); a2.y = fmaf(a2.y, sc_, p_*V2_.y); \
    a2.z = fmaf(a2.z, sc_, p_*V2_.z); a2.w = fmaf(a2.w, sc_, p_*V2_.w); \
    a3.x = fmaf(a3.x, sc_, p_*V3_.x); a3.y = fmaf(a3.y, sc_, p_*V3_.y); \
    a3.z = fmaf(a3.z, sc_, p_*V3_.z); a3.w = fmaf(a3.w, sc_, p_*V3_.w); \
    l = fmaf(l, sc_, p_); m = mn_; }

    // ping-pong prefetch: load batch k+1 while processing batch k
    float4 A0 = make_float4(0,0,0,0), A1 = A0, A2 = A0, A3 = A0;
    float4 B0 = A0, B1 = A0, B2 = A0, B3 = A0;
    bool okA = false, okB = false;

    if (n > 0) { int r; POP(r, okA); LOADV(A0, A1, A2, A3, r, okA); }
    int it = 0;
    while (it < n) {
        if (it + 1 < n) { int r; POP(r, okB); LOADV(B0, B1, B2, B3, r, okB); }
        PROC(A0, A1, A2, A3, okA);
        if (++it >= n) break;
        if (it + 1 < n) { int r; POP(r, okA); LOADV(A0, A1, A2, A3, r, okA); }
        PROC(B0, B1, B2, B3, okB);
        if (++it >= n) break;
    }

    // --- merge the block's 8 group-partials via LDS ---
    __shared__ float sm[8];
    __shared__ float sl[8];
    __shared__ float sz[8][DD];   // 8 KB

    *(float4*)&sz[grp][i * 4      ] = a0;
    *(float4*)&sz[grp][i * 4 + 64 ] = a1;
    *(float4*)&sz[grp][i * 4 + 128] = a2;
    *(float4*)&sz[grp][i * 4 + 192] = a3;
    if (i == 0) { sm[grp] = m; sl[grp] = l; }
    __syncthreads();

    // thread tid owns output dims d = tid and tid+128
    float M = -3.0e38f;
    #pragma unroll
    for (int k = 0; k < 8; ++k) M = fmaxf(M, sm[k]);
    float L = 0.f, Z0 = 0.f, Z1 = 0.f;
    #pragma unroll
    for (int k = 0; k < 8; ++k) {
        float e = __expf(sm[k] - M);   // empty group: l=0 kills it
        L  = fmaf(sl[k], e, L);
        Z0 = fmaf(sz[k][tid], e, Z0);
        Z1 = fmaf(sz[k][tid + 128], e, Z1);
    }
    if (tid == 0) { msv[blk] = M; lsv[blk] = L; }
    zsv[(size_t)blk * DD + tid]       = Z0;
    zsv[(size_t)blk * DD + tid + 128] = Z1;
#undef POP
#undef LOADV
#undef PROC
}

__global__ __launch_bounds__(128) void soft_att_combine(
    const float* __restrict__ msv,
    const float* __restrict__ lsv,
    const float* __restrict__ zsv,
    float* __restrict__ out)          // [B, D]
{
    const int blk = blockIdx.x;           // 256 blocks: (b, half)
    const int b   = blk >> 1;
    const int d   = ((blk & 1) << 7) + threadIdx.x;

    float M = -3.0e38f;
    #pragma unroll
    for (int p = 0; p < NCHUNK; ++p)
        M = fmaxf(M, msv[b * NCHUNK + p]);

    float L = 0.f, Z = 0.f;
    #pragma unroll
    for (int p = 0; p < NCHUNK; ++p) {
        float e = __expf(msv[b * NCHUNK + p] - M);
        L = fmaf(lsv[b * NCHUNK + p], e, L);
        Z = fmaf(zsv[(size_t)(b * NCHUNK + p) * DD + d], e, Z);
    }
    out[(size_t)b * DD + d] = Z / L;
}

extern "C" void kernel_launch(void* const* d_in, const int* in_sizes, int n_in,
                              void* d_out, int out_size, void* d_ws, size_t ws_size,
                              hipStream_t stream) {
    const float* h     = (const float*)d_in[0];
    const float* htraj = (const float*)d_in[1];
    const int*   mask  = (const int*)d_in[2];
    const float* w     = (const float*)d_in[3];
    const float* bias  = (const float*)d_in[4];
    float* out = (float*)d_out;

    float* ms = (float*)d_ws;
    float* ls = ms + NPART;
    float* zs = ls + NPART;

    soft_att_partial<<<dim3(BB * NCHUNK), dim3(128), 0, stream>>>(
        h, htraj, mask, w, bias, ms, ls, zs);
    soft_att_combine<<<dim3(BB * 2), dim3(128), 0, stream>>>(ms, ls, zs, out);
}